// Round 3
// baseline (725.008 us; speedup 1.0000x reference)
//
#include <hip/hip_runtime.h>
#include <hip/hip_bf16.h>
#include <cstdint>

#define DIM 128
#define BK_SHIFT 7
#define BK_NODES 128          // nodes per bucket = 1 << BK_SHIFT
#define MAX_BUCKETS 1024      // supports N <= 131072

// ---------------- pass 1: per-bucket edge counts (LDS histogram) ----------------
__global__ __launch_bounds__(256) void bucket_hist_kernel(const int* __restrict__ dst,
                                                          int* __restrict__ bcount,
                                                          int E, int nbk) {
    __shared__ int h[MAX_BUCKETS];
    for (int i = threadIdx.x; i < nbk; i += 256) h[i] = 0;
    __syncthreads();
    int base = blockIdx.x * 2048;
    #pragma unroll
    for (int k = 0; k < 8; ++k) {
        int e = base + k * 256 + threadIdx.x;
        if (e < E) atomicAdd(&h[dst[e] >> BK_SHIFT], 1);
    }
    __syncthreads();
    for (int i = threadIdx.x; i < nbk; i += 256) {
        int v = h[i];
        if (v) atomicAdd(&bcount[i], v);
    }
}

// ---------------- pass 2: exclusive scan of bucket counts (single block) ----------------
__global__ __launch_bounds__(MAX_BUCKETS) void bucket_scan_kernel(const int* __restrict__ bcount,
                                                                  int* __restrict__ boff,
                                                                  int* __restrict__ bcursor,
                                                                  int* __restrict__ offsets,
                                                                  int nbk, int N, int E) {
    __shared__ int s[MAX_BUCKETS];
    int tid = threadIdx.x;
    int c = (tid < nbk) ? bcount[tid] : 0;
    s[tid] = c;
    __syncthreads();
    for (int d = 1; d < MAX_BUCKETS; d <<= 1) {
        int v = (tid >= d) ? s[tid - d] : 0;
        __syncthreads();
        s[tid] += v;
        __syncthreads();
    }
    if (tid < nbk) {
        boff[tid + 1] = s[tid];          // inclusive -> end offset of bucket tid
        bcursor[tid]  = s[tid] - c;      // exclusive -> start offset
    }
    if (tid == 0) {
        boff[0] = 0;
        offsets[N] = E;                  // CSR sentinel
    }
}

// ---------------- pass 3: scatter edges to bucket-major buffer (packed) ----------------
__global__ __launch_bounds__(256) void bucket_scatter_kernel(const int* __restrict__ src,
                                                             const int* __restrict__ dst,
                                                             int* __restrict__ bcursor,
                                                             int* __restrict__ bbuf, int E) {
    int e = blockIdx.x * 256 + threadIdx.x;
    if (e < E) {
        int d = dst[e];
        int pos = atomicAdd(&bcursor[d >> BK_SHIFT], 1);
        bbuf[pos] = (src[e] << BK_SHIFT) | (d & (BK_NODES - 1));
    }
}

// ---------------- pass 4: per-bucket CSR build (offsets, dinv, csr_src) ----------------
__global__ __launch_bounds__(256) void build_csr_kernel(const int* __restrict__ bbuf,
                                                        const int* __restrict__ boff,
                                                        int* __restrict__ offsets,
                                                        float* __restrict__ dinv,
                                                        int* __restrict__ csr_src,
                                                        int N) {
    __shared__ int cnt[BK_NODES];
    __shared__ int sc[BK_NODES];
    __shared__ int cur[BK_NODES];
    int b = blockIdx.x, tid = threadIdx.x;
    int beg = boff[b], end = boff[b + 1];
    if (tid < BK_NODES) cnt[tid] = 0;
    __syncthreads();
    for (int j = beg + tid; j < end; j += 256)
        atomicAdd(&cnt[bbuf[j] & (BK_NODES - 1)], 1);
    __syncthreads();
    if (tid < BK_NODES) sc[tid] = cnt[tid];
    __syncthreads();
    for (int d = 1; d < BK_NODES; d <<= 1) {
        int v = (tid >= d && tid < BK_NODES) ? sc[tid - d] : 0;
        __syncthreads();
        if (tid < BK_NODES) sc[tid] += v;
        __syncthreads();
    }
    if (tid < BK_NODES) {
        int node = b * BK_NODES + tid;
        int start = beg + sc[tid] - cnt[tid];
        cur[tid] = start;
        if (node < N) {
            offsets[node] = start;
            dinv[node] = rsqrtf((float)(cnt[tid] + 1));   // +1 self loop
        }
    }
    __syncthreads();
    for (int j = beg + tid; j < end; j += 256) {
        int packed = bbuf[j];
        int pos = atomicAdd(&cur[packed & (BK_NODES - 1)], 1);
        csr_src[pos] = packed >> BK_SHIFT;
    }
}

// ---------------- pre-scale: y[i] = dinv[i] * x[i] (row-wise) ----------------
__global__ __launch_bounds__(256) void prescale_kernel(const float* __restrict__ x,
                                                       const float* __restrict__ dinv,
                                                       float* __restrict__ y, int N) {
    int t = blockIdx.x * 256 + threadIdx.x;
    int total = N * (DIM / 4);
    if (t < total) {
        int row = t >> 5;
        float di = dinv[row];
        float4 v = ((const float4*)x)[t];
        v.x *= di; v.y *= di; v.z *= di; v.w *= di;
        ((float4*)y)[t] = v;
    }
}

// ---------------- aggregation (pre-scaled): out[d] = dinv[d]*(y[d] + sum_e y[src]) ----------------
__global__ __launch_bounds__(256) void agg_kernel(const float* __restrict__ y,
                                                  const int* __restrict__ csr_src,
                                                  const int* __restrict__ offsets,
                                                  const float* __restrict__ dinv,
                                                  float* __restrict__ out, int N) {
    int lane = threadIdx.x & 63;
    int wid  = __builtin_amdgcn_readfirstlane((int)(threadIdx.x >> 6));
    int node = blockIdx.x * 4 + wid;
    if (node >= N) return;
    int beg = offsets[node];
    int end = offsets[node + 1];
    float di = dinv[node];
    float2 acc = ((const float2*)(y + (size_t)node * DIM))[lane];  // self term
    int j = beg;
    for (; j + 4 <= end; j += 4) {
        int s0 = csr_src[j + 0], s1 = csr_src[j + 1];
        int s2 = csr_src[j + 2], s3 = csr_src[j + 3];
        float2 v0 = ((const float2*)(y + (size_t)s0 * DIM))[lane];
        float2 v1 = ((const float2*)(y + (size_t)s1 * DIM))[lane];
        float2 v2 = ((const float2*)(y + (size_t)s2 * DIM))[lane];
        float2 v3 = ((const float2*)(y + (size_t)s3 * DIM))[lane];
        acc.x += v0.x; acc.y += v0.y;
        acc.x += v1.x; acc.y += v1.y;
        acc.x += v2.x; acc.y += v2.y;
        acc.x += v3.x; acc.y += v3.y;
    }
    for (; j < end; ++j) {
        int s = csr_src[j];
        float2 v = ((const float2*)(y + (size_t)s * DIM))[lane];
        acc.x += v.x; acc.y += v.y;
    }
    acc.x *= di; acc.y *= di;
    ((float2*)(out + (size_t)node * DIM))[lane] = acc;
}

// ---------------- aggregation fallback (no y buffer): fused dinv ----------------
__global__ __launch_bounds__(256) void agg_fused_kernel(const float* __restrict__ x,
                                                        const int* __restrict__ csr_src,
                                                        const int* __restrict__ offsets,
                                                        const float* __restrict__ dinv,
                                                        float* __restrict__ out, int N) {
    int lane = threadIdx.x & 63;
    int wid  = __builtin_amdgcn_readfirstlane((int)(threadIdx.x >> 6));
    int node = blockIdx.x * 4 + wid;
    if (node >= N) return;
    int beg = offsets[node];
    int end = offsets[node + 1];
    float di = dinv[node];
    float2 acc = ((const float2*)(x + (size_t)node * DIM))[lane];
    acc.x *= di; acc.y *= di;
    int j = beg;
    for (; j + 4 <= end; j += 4) {
        int s0 = csr_src[j + 0], s1 = csr_src[j + 1];
        int s2 = csr_src[j + 2], s3 = csr_src[j + 3];
        float w0 = dinv[s0], w1 = dinv[s1], w2 = dinv[s2], w3 = dinv[s3];
        float2 v0 = ((const float2*)(x + (size_t)s0 * DIM))[lane];
        float2 v1 = ((const float2*)(x + (size_t)s1 * DIM))[lane];
        float2 v2 = ((const float2*)(x + (size_t)s2 * DIM))[lane];
        float2 v3 = ((const float2*)(x + (size_t)s3 * DIM))[lane];
        acc.x += w0 * v0.x; acc.y += w0 * v0.y;
        acc.x += w1 * v1.x; acc.y += w1 * v1.y;
        acc.x += w2 * v2.x; acc.y += w2 * v2.y;
        acc.x += w3 * v3.x; acc.y += w3 * v3.y;
    }
    for (; j < end; ++j) {
        int s = csr_src[j];
        float w = dinv[s];
        float2 v = ((const float2*)(x + (size_t)s * DIM))[lane];
        acc.x += w * v.x; acc.y += w * v.y;
    }
    acc.x *= di; acc.y *= di;
    ((float2*)(out + (size_t)node * DIM))[lane] = acc;
}

// ---------------- in-place GEMM + bias + PReLU: io = prelu(io @ W + b) ----------------
__global__ __launch_bounds__(256) void gemm_kernel(float* __restrict__ io,
                                                   const float* __restrict__ W,
                                                   const float* __restrict__ b,
                                                   const float* __restrict__ alpha, int N) {
    int lane = threadIdx.x & 63;
    int wid  = __builtin_amdgcn_readfirstlane((int)(threadIdx.x >> 6));
    int rowbase = (blockIdx.x * 4 + wid) * 8;
    const int c0 = lane, c1 = lane + 64;
    float acc0[8], acc1[8];
    #pragma unroll
    for (int r = 0; r < 8; ++r) { acc0[r] = 0.f; acc1[r] = 0.f; }
    for (int k = 0; k < DIM; k += 4) {
        float w00 = W[(k + 0) * DIM + c0], w01 = W[(k + 1) * DIM + c0];
        float w02 = W[(k + 2) * DIM + c0], w03 = W[(k + 3) * DIM + c0];
        float w10 = W[(k + 0) * DIM + c1], w11 = W[(k + 1) * DIM + c1];
        float w12 = W[(k + 2) * DIM + c1], w13 = W[(k + 3) * DIM + c1];
        #pragma unroll
        for (int r = 0; r < 8; ++r) {
            int row = rowbase + r;
            row = row < N ? row : N - 1;
            float4 rv = ((const float4*)(io + (size_t)row * DIM))[k >> 2];
            acc0[r] += rv.x * w00 + rv.y * w01 + rv.z * w02 + rv.w * w03;
            acc1[r] += rv.x * w10 + rv.y * w11 + rv.z * w12 + rv.w * w13;
        }
    }
    float bb0 = b[c0], bb1 = b[c1], a0 = alpha[c0], a1 = alpha[c1];
    #pragma unroll
    for (int r = 0; r < 8; ++r) {
        int row = rowbase + r;
        if (row < N) {
            float v0 = acc0[r] + bb0; v0 = v0 > 0.f ? v0 : a0 * v0;
            float v1 = acc1[r] + bb1; v1 = v1 > 0.f ? v1 : a1 * v1;
            io[(size_t)row * DIM + c0] = v0;
            io[(size_t)row * DIM + c1] = v1;
        }
    }
}

extern "C" void kernel_launch(void* const* d_in, const int* in_sizes, int n_in,
                              void* d_out, int out_size, void* d_ws, size_t ws_size,
                              hipStream_t stream) {
    const float* x     = (const float*)d_in[0];
    const int*   ei    = (const int*)d_in[1];
    const float* W     = (const float*)d_in[2];
    const float* b     = (const float*)d_in[3];
    const float* alpha = (const float*)d_in[4];
    float* out = (float*)d_out;

    int N = in_sizes[0] / DIM;
    int E = in_sizes[1] / 2;
    const int* src = ei;
    const int* dst = ei + E;
    int nbk = (N + BK_NODES - 1) >> BK_SHIFT;      // 782 for N=100000

    char* ws = (char*)d_ws;
    size_t off = 0;
    auto alloc = [&](size_t bytes) -> char* {
        char* p = ws + off;
        off += (bytes + 255) & ~(size_t)255;
        return p;
    };
    int*   bcount  = (int*)alloc((size_t)MAX_BUCKETS * 4);
    int*   boff    = (int*)alloc((size_t)(MAX_BUCKETS + 1) * 4);
    int*   bcursor = (int*)alloc((size_t)MAX_BUCKETS * 4);
    int*   offsets = (int*)alloc((size_t)(N + 1) * 4);
    float* dinv    = (float*)alloc((size_t)N * 4);
    int*   bbuf    = (int*)alloc((size_t)E * 4);
    int*   csr_src = (int*)alloc((size_t)E * 4);
    size_t y_bytes = (size_t)N * DIM * 4;
    bool   have_y  = (off + y_bytes) <= ws_size;
    float* y       = have_y ? (float*)alloc(y_bytes) : nullptr;

    hipMemsetAsync(bcount, 0, (size_t)nbk * 4, stream);
    bucket_hist_kernel<<<(E + 2047) / 2048, 256, 0, stream>>>(dst, bcount, E, nbk);
    bucket_scan_kernel<<<1, MAX_BUCKETS, 0, stream>>>(bcount, boff, bcursor, offsets, nbk, N, E);
    bucket_scatter_kernel<<<(E + 255) / 256, 256, 0, stream>>>(src, dst, bcursor, bbuf, E);
    build_csr_kernel<<<nbk, 256, 0, stream>>>(bbuf, boff, offsets, dinv, csr_src, N);
    if (have_y) {
        prescale_kernel<<<(N * (DIM / 4) + 255) / 256, 256, 0, stream>>>(x, dinv, y, N);
        agg_kernel<<<(N + 3) / 4, 256, 0, stream>>>(y, csr_src, offsets, dinv, out, N);
    } else {
        agg_fused_kernel<<<(N + 3) / 4, 256, 0, stream>>>(x, csr_src, offsets, dinv, out, N);
    }
    gemm_kernel<<<(N + 31) / 32, 256, 0, stream>>>(out, W, b, alpha, N);
}

// Round 4
// 380.400 us; speedup vs baseline: 1.9059x; 1.9059x over previous
//
#include <hip/hip_runtime.h>
#include <hip/hip_bf16.h>
#include <cstdint>

#define DIM 128
#define BK_SHIFT 7
#define BK_NODES 128          // nodes per bucket = 1 << BK_SHIFT
#define MAX_BUCKETS 1024      // supports N <= 131072
#define CUR_STRIDE 16         // pad bucket cursors: 1 per 64B line
#define ST 4096               // edges per scatter block
#define EPT 16                // edges per thread (ST/256)

// ---------------- pass 1: per-bucket edge counts (LDS histogram) ----------------
__global__ __launch_bounds__(256) void bucket_hist_kernel(const int* __restrict__ dst,
                                                          int* __restrict__ bcount,
                                                          int E, int nbk) {
    __shared__ int h[MAX_BUCKETS];
    for (int i = threadIdx.x; i < nbk; i += 256) h[i] = 0;
    __syncthreads();
    int base = blockIdx.x * 2048;
    #pragma unroll
    for (int k = 0; k < 8; ++k) {
        int e = base + k * 256 + threadIdx.x;
        if (e < E) atomicAdd(&h[dst[e] >> BK_SHIFT], 1);
    }
    __syncthreads();
    for (int i = threadIdx.x; i < nbk; i += 256) {
        int v = h[i];
        if (v) atomicAdd(&bcount[i], v);
    }
}

// ---------------- pass 2: exclusive scan of bucket counts (single block) ----------------
__global__ __launch_bounds__(MAX_BUCKETS) void bucket_scan_kernel(const int* __restrict__ bcount,
                                                                  int* __restrict__ boff,
                                                                  int* __restrict__ bcursor,
                                                                  int* __restrict__ offsets,
                                                                  int nbk, int N, int E) {
    __shared__ int s[MAX_BUCKETS];
    int tid = threadIdx.x;
    int c = (tid < nbk) ? bcount[tid] : 0;
    s[tid] = c;
    __syncthreads();
    for (int d = 1; d < MAX_BUCKETS; d <<= 1) {
        int v = (tid >= d) ? s[tid - d] : 0;
        __syncthreads();
        s[tid] += v;
        __syncthreads();
    }
    if (tid < nbk) {
        boff[tid + 1] = s[tid];                    // inclusive -> end offset of bucket tid
        bcursor[tid * CUR_STRIDE] = s[tid] - c;    // exclusive -> start offset (line-padded)
    }
    if (tid == 0) {
        boff[0] = 0;
        offsets[N] = E;                            // CSR sentinel
    }
}

// ---------------- pass 3: block-aggregated scatter to bucket-major buffer ----------------
// Each block: LDS histogram + per-edge rank -> one global atomic per (block,bucket)
// reserving a contiguous run -> direct stores into the run. Cursors line-padded to
// avoid cross-XCD same-line atomic ping-pong (R3: 11.5 ns/same-line atomic).
__global__ __launch_bounds__(256) void bucket_scatter_kernel(const int* __restrict__ src,
                                                             const int* __restrict__ dst,
                                                             int* __restrict__ bcursor,
                                                             int* __restrict__ bbuf,
                                                             int E, int nbk) {
    __shared__ int h[MAX_BUCKETS];   // count, then base
    for (int i = threadIdx.x; i < nbk; i += 256) h[i] = 0;
    __syncthreads();
    int base = blockIdx.x * ST;
    int bk[EPT], rk[EPT], pk[EPT];
    #pragma unroll
    for (int k = 0; k < EPT; ++k) {
        int e = base + k * 256 + threadIdx.x;
        bk[k] = -1;
        if (e < E) {
            int d = dst[e];
            int b = d >> BK_SHIFT;
            bk[k] = b;
            pk[k] = (src[e] << BK_SHIFT) | (d & (BK_NODES - 1));
            rk[k] = atomicAdd(&h[b], 1);
        }
    }
    __syncthreads();
    for (int i = threadIdx.x; i < nbk; i += 256) {
        int c = h[i];
        h[i] = c ? atomicAdd(&bcursor[i * CUR_STRIDE], c) : 0;
    }
    __syncthreads();
    #pragma unroll
    for (int k = 0; k < EPT; ++k) {
        if (bk[k] >= 0) bbuf[h[bk[k]] + rk[k]] = pk[k];
    }
}

// ---------------- pass 4: per-bucket CSR build (offsets, dinv, csr_src) ----------------
__global__ __launch_bounds__(256) void build_csr_kernel(const int* __restrict__ bbuf,
                                                        const int* __restrict__ boff,
                                                        int* __restrict__ offsets,
                                                        float* __restrict__ dinv,
                                                        int* __restrict__ csr_src,
                                                        int N) {
    __shared__ int cnt[BK_NODES];
    __shared__ int sc[BK_NODES];
    __shared__ int cur[BK_NODES];
    int b = blockIdx.x, tid = threadIdx.x;
    int beg = boff[b], end = boff[b + 1];
    if (tid < BK_NODES) cnt[tid] = 0;
    __syncthreads();
    for (int j = beg + tid; j < end; j += 256)
        atomicAdd(&cnt[bbuf[j] & (BK_NODES - 1)], 1);
    __syncthreads();
    if (tid < BK_NODES) sc[tid] = cnt[tid];
    __syncthreads();
    for (int d = 1; d < BK_NODES; d <<= 1) {
        int v = (tid >= d && tid < BK_NODES) ? sc[tid - d] : 0;
        __syncthreads();
        if (tid < BK_NODES) sc[tid] += v;
        __syncthreads();
    }
    if (tid < BK_NODES) {
        int node = b * BK_NODES + tid;
        int start = beg + sc[tid] - cnt[tid];
        cur[tid] = start;
        if (node < N) {
            offsets[node] = start;
            dinv[node] = rsqrtf((float)(cnt[tid] + 1));   // +1 self loop
        }
    }
    __syncthreads();
    for (int j = beg + tid; j < end; j += 256) {
        int packed = bbuf[j];
        int pos = atomicAdd(&cur[packed & (BK_NODES - 1)], 1);
        csr_src[pos] = packed >> BK_SHIFT;
    }
}

// ---------------- pre-scale: y[i] = dinv[i] * x[i] (row-wise) ----------------
__global__ __launch_bounds__(256) void prescale_kernel(const float* __restrict__ x,
                                                       const float* __restrict__ dinv,
                                                       float* __restrict__ y, int N) {
    int t = blockIdx.x * 256 + threadIdx.x;
    int total = N * (DIM / 4);
    if (t < total) {
        int row = t >> 5;
        float di = dinv[row];
        float4 v = ((const float4*)x)[t];
        v.x *= di; v.y *= di; v.z *= di; v.w *= di;
        ((float4*)y)[t] = v;
    }
}

// ---------------- aggregation (pre-scaled): out[d] = dinv[d]*(y[d] + sum_e y[src]) ----------------
__global__ __launch_bounds__(256) void agg_kernel(const float* __restrict__ y,
                                                  const int* __restrict__ csr_src,
                                                  const int* __restrict__ offsets,
                                                  const float* __restrict__ dinv,
                                                  float* __restrict__ out, int N) {
    int lane = threadIdx.x & 63;
    int wid  = __builtin_amdgcn_readfirstlane((int)(threadIdx.x >> 6));
    int node = blockIdx.x * 4 + wid;
    if (node >= N) return;
    int beg = offsets[node];
    int end = offsets[node + 1];
    float di = dinv[node];
    float2 acc = ((const float2*)(y + (size_t)node * DIM))[lane];  // self term
    int j = beg;
    for (; j + 4 <= end; j += 4) {
        int s0 = csr_src[j + 0], s1 = csr_src[j + 1];
        int s2 = csr_src[j + 2], s3 = csr_src[j + 3];
        float2 v0 = ((const float2*)(y + (size_t)s0 * DIM))[lane];
        float2 v1 = ((const float2*)(y + (size_t)s1 * DIM))[lane];
        float2 v2 = ((const float2*)(y + (size_t)s2 * DIM))[lane];
        float2 v3 = ((const float2*)(y + (size_t)s3 * DIM))[lane];
        acc.x += v0.x; acc.y += v0.y;
        acc.x += v1.x; acc.y += v1.y;
        acc.x += v2.x; acc.y += v2.y;
        acc.x += v3.x; acc.y += v3.y;
    }
    for (; j < end; ++j) {
        int s = csr_src[j];
        float2 v = ((const float2*)(y + (size_t)s * DIM))[lane];
        acc.x += v.x; acc.y += v.y;
    }
    acc.x *= di; acc.y *= di;
    ((float2*)(out + (size_t)node * DIM))[lane] = acc;
}

// ---------------- aggregation fallback (no y buffer): fused dinv ----------------
__global__ __launch_bounds__(256) void agg_fused_kernel(const float* __restrict__ x,
                                                        const int* __restrict__ csr_src,
                                                        const int* __restrict__ offsets,
                                                        const float* __restrict__ dinv,
                                                        float* __restrict__ out, int N) {
    int lane = threadIdx.x & 63;
    int wid  = __builtin_amdgcn_readfirstlane((int)(threadIdx.x >> 6));
    int node = blockIdx.x * 4 + wid;
    if (node >= N) return;
    int beg = offsets[node];
    int end = offsets[node + 1];
    float di = dinv[node];
    float2 acc = ((const float2*)(x + (size_t)node * DIM))[lane];
    acc.x *= di; acc.y *= di;
    int j = beg;
    for (; j + 4 <= end; j += 4) {
        int s0 = csr_src[j + 0], s1 = csr_src[j + 1];
        int s2 = csr_src[j + 2], s3 = csr_src[j + 3];
        float w0 = dinv[s0], w1 = dinv[s1], w2 = dinv[s2], w3 = dinv[s3];
        float2 v0 = ((const float2*)(x + (size_t)s0 * DIM))[lane];
        float2 v1 = ((const float2*)(x + (size_t)s1 * DIM))[lane];
        float2 v2 = ((const float2*)(x + (size_t)s2 * DIM))[lane];
        float2 v3 = ((const float2*)(x + (size_t)s3 * DIM))[lane];
        acc.x += w0 * v0.x; acc.y += w0 * v0.y;
        acc.x += w1 * v1.x; acc.y += w1 * v1.y;
        acc.x += w2 * v2.x; acc.y += w2 * v2.y;
        acc.x += w3 * v3.x; acc.y += w3 * v3.y;
    }
    for (; j < end; ++j) {
        int s = csr_src[j];
        float w = dinv[s];
        float2 v = ((const float2*)(x + (size_t)s * DIM))[lane];
        acc.x += w * v.x; acc.y += w * v.y;
    }
    acc.x *= di; acc.y *= di;
    ((float2*)(out + (size_t)node * DIM))[lane] = acc;
}

// ---------------- in-place GEMM + bias + PReLU: io = prelu(io @ W + b) ----------------
__global__ __launch_bounds__(256) void gemm_kernel(float* __restrict__ io,
                                                   const float* __restrict__ W,
                                                   const float* __restrict__ b,
                                                   const float* __restrict__ alpha, int N) {
    int lane = threadIdx.x & 63;
    int wid  = __builtin_amdgcn_readfirstlane((int)(threadIdx.x >> 6));
    int rowbase = (blockIdx.x * 4 + wid) * 8;
    const int c0 = lane, c1 = lane + 64;
    float acc0[8], acc1[8];
    #pragma unroll
    for (int r = 0; r < 8; ++r) { acc0[r] = 0.f; acc1[r] = 0.f; }
    for (int k = 0; k < DIM; k += 4) {
        float w00 = W[(k + 0) * DIM + c0], w01 = W[(k + 1) * DIM + c0];
        float w02 = W[(k + 2) * DIM + c0], w03 = W[(k + 3) * DIM + c0];
        float w10 = W[(k + 0) * DIM + c1], w11 = W[(k + 1) * DIM + c1];
        float w12 = W[(k + 2) * DIM + c1], w13 = W[(k + 3) * DIM + c1];
        #pragma unroll
        for (int r = 0; r < 8; ++r) {
            int row = rowbase + r;
            row = row < N ? row : N - 1;
            float4 rv = ((const float4*)(io + (size_t)row * DIM))[k >> 2];
            acc0[r] += rv.x * w00 + rv.y * w01 + rv.z * w02 + rv.w * w03;
            acc1[r] += rv.x * w10 + rv.y * w11 + rv.z * w12 + rv.w * w13;
        }
    }
    float bb0 = b[c0], bb1 = b[c1], a0 = alpha[c0], a1 = alpha[c1];
    #pragma unroll
    for (int r = 0; r < 8; ++r) {
        int row = rowbase + r;
        if (row < N) {
            float v0 = acc0[r] + bb0; v0 = v0 > 0.f ? v0 : a0 * v0;
            float v1 = acc1[r] + bb1; v1 = v1 > 0.f ? v1 : a1 * v1;
            io[(size_t)row * DIM + c0] = v0;
            io[(size_t)row * DIM + c1] = v1;
        }
    }
}

extern "C" void kernel_launch(void* const* d_in, const int* in_sizes, int n_in,
                              void* d_out, int out_size, void* d_ws, size_t ws_size,
                              hipStream_t stream) {
    const float* x     = (const float*)d_in[0];
    const int*   ei    = (const int*)d_in[1];
    const float* W     = (const float*)d_in[2];
    const float* b     = (const float*)d_in[3];
    const float* alpha = (const float*)d_in[4];
    float* out = (float*)d_out;

    int N = in_sizes[0] / DIM;
    int E = in_sizes[1] / 2;
    const int* src = ei;
    const int* dst = ei + E;
    int nbk = (N + BK_NODES - 1) >> BK_SHIFT;      // 782 for N=100000

    char* ws = (char*)d_ws;
    size_t off = 0;
    auto alloc = [&](size_t bytes) -> char* {
        char* p = ws + off;
        off += (bytes + 255) & ~(size_t)255;
        return p;
    };
    int*   bcount  = (int*)alloc((size_t)MAX_BUCKETS * 4);
    int*   boff    = (int*)alloc((size_t)(MAX_BUCKETS + 1) * 4);
    int*   bcursor = (int*)alloc((size_t)MAX_BUCKETS * CUR_STRIDE * 4);  // line-padded
    int*   offsets = (int*)alloc((size_t)(N + 1) * 4);
    float* dinv    = (float*)alloc((size_t)N * 4);
    int*   bbuf    = (int*)alloc((size_t)E * 4);
    int*   csr_src = (int*)alloc((size_t)E * 4);
    size_t y_bytes = (size_t)N * DIM * 4;
    bool   have_y  = (off + y_bytes) <= ws_size;
    float* y       = have_y ? (float*)alloc(y_bytes) : nullptr;

    hipMemsetAsync(bcount, 0, (size_t)nbk * 4, stream);
    bucket_hist_kernel<<<(E + 2047) / 2048, 256, 0, stream>>>(dst, bcount, E, nbk);
    bucket_scan_kernel<<<1, MAX_BUCKETS, 0, stream>>>(bcount, boff, bcursor, offsets, nbk, N, E);
    bucket_scatter_kernel<<<(E + ST - 1) / ST, 256, 0, stream>>>(src, dst, bcursor, bbuf, E, nbk);
    build_csr_kernel<<<nbk, 256, 0, stream>>>(bbuf, boff, offsets, dinv, csr_src, N);
    if (have_y) {
        prescale_kernel<<<(N * (DIM / 4) + 255) / 256, 256, 0, stream>>>(x, dinv, y, N);
        agg_kernel<<<(N + 3) / 4, 256, 0, stream>>>(y, csr_src, offsets, dinv, out, N);
    } else {
        agg_fused_kernel<<<(N + 3) / 4, 256, 0, stream>>>(x, csr_src, offsets, dinv, out, N);
    }
    gemm_kernel<<<(N + 31) / 32, 256, 0, stream>>>(out, W, b, alpha, N);
}

// Round 5
// 278.376 us; speedup vs baseline: 2.6044x; 1.3665x over previous
//
#include <hip/hip_runtime.h>
#include <hip/hip_bf16.h>
#include <cstdint>

#define DIM 128
#define BK_SHIFT 7
#define BK_NODES 128          // nodes per bucket = 1 << BK_SHIFT
#define MAX_BUCKETS 1024      // supports N <= 131072
#define CUR_STRIDE 16         // pad bucket cursors: 1 per 64B line
#define ST 4096               // edges per scatter block
#define EPT 16                // edges per thread (ST/256)

typedef float f32x4  __attribute__((ext_vector_type(4)));
typedef short bf16x8 __attribute__((ext_vector_type(8)));   // 8 bf16 in 4 VGPRs

__device__ __forceinline__ unsigned bf16_rne(float f) {
    unsigned u = __float_as_uint(f);
    return (u + 0x7fffu + ((u >> 16) & 1u)) >> 16;   // round-to-nearest-even
}

// ---------------- pass 1: per-bucket edge counts (LDS histogram) ----------------
__global__ __launch_bounds__(256) void bucket_hist_kernel(const int* __restrict__ dst,
                                                          int* __restrict__ bcount,
                                                          int E, int nbk) {
    __shared__ int h[MAX_BUCKETS];
    for (int i = threadIdx.x; i < nbk; i += 256) h[i] = 0;
    __syncthreads();
    int base = blockIdx.x * 2048;
    #pragma unroll
    for (int k = 0; k < 8; ++k) {
        int e = base + k * 256 + threadIdx.x;
        if (e < E) atomicAdd(&h[dst[e] >> BK_SHIFT], 1);
    }
    __syncthreads();
    for (int i = threadIdx.x; i < nbk; i += 256) {
        int v = h[i];
        if (v) atomicAdd(&bcount[i], v);
    }
}

// ---------------- pass 2: exclusive scan of bucket counts (single block) ----------------
__global__ __launch_bounds__(MAX_BUCKETS) void bucket_scan_kernel(const int* __restrict__ bcount,
                                                                  int* __restrict__ boff,
                                                                  int* __restrict__ bcursor,
                                                                  int* __restrict__ offsets,
                                                                  int nbk, int N, int E) {
    __shared__ int s[MAX_BUCKETS];
    int tid = threadIdx.x;
    int c = (tid < nbk) ? bcount[tid] : 0;
    s[tid] = c;
    __syncthreads();
    for (int d = 1; d < MAX_BUCKETS; d <<= 1) {
        int v = (tid >= d) ? s[tid - d] : 0;
        __syncthreads();
        s[tid] += v;
        __syncthreads();
    }
    if (tid < nbk) {
        boff[tid + 1] = s[tid];                    // inclusive -> end offset of bucket tid
        bcursor[tid * CUR_STRIDE] = s[tid] - c;    // exclusive -> start offset (line-padded)
    }
    if (tid == 0) {
        boff[0] = 0;
        offsets[N] = E;                            // CSR sentinel
    }
}

// ---------------- pass 3: block-aggregated scatter to bucket-major buffer ----------------
__global__ __launch_bounds__(256) void bucket_scatter_kernel(const int* __restrict__ src,
                                                             const int* __restrict__ dst,
                                                             int* __restrict__ bcursor,
                                                             int* __restrict__ bbuf,
                                                             int E, int nbk) {
    __shared__ int h[MAX_BUCKETS];   // count, then base
    for (int i = threadIdx.x; i < nbk; i += 256) h[i] = 0;
    __syncthreads();
    int base = blockIdx.x * ST;
    int bk[EPT], rk[EPT], pk[EPT];
    #pragma unroll
    for (int k = 0; k < EPT; ++k) {
        int e = base + k * 256 + threadIdx.x;
        bk[k] = -1;
        if (e < E) {
            int d = dst[e];
            int b = d >> BK_SHIFT;
            bk[k] = b;
            pk[k] = (src[e] << BK_SHIFT) | (d & (BK_NODES - 1));
            rk[k] = atomicAdd(&h[b], 1);
        }
    }
    __syncthreads();
    for (int i = threadIdx.x; i < nbk; i += 256) {
        int c = h[i];
        h[i] = c ? atomicAdd(&bcursor[i * CUR_STRIDE], c) : 0;
    }
    __syncthreads();
    #pragma unroll
    for (int k = 0; k < EPT; ++k) {
        if (bk[k] >= 0) bbuf[h[bk[k]] + rk[k]] = pk[k];
    }
}

// ---------------- pass 4: per-bucket CSR build (offsets, dinv, csr_src) ----------------
__global__ __launch_bounds__(256) void build_csr_kernel(const int* __restrict__ bbuf,
                                                        const int* __restrict__ boff,
                                                        int* __restrict__ offsets,
                                                        float* __restrict__ dinv,
                                                        int* __restrict__ csr_src,
                                                        int N) {
    __shared__ int cnt[BK_NODES];
    __shared__ int sc[BK_NODES];
    __shared__ int cur[BK_NODES];
    int b = blockIdx.x, tid = threadIdx.x;
    int beg = boff[b], end = boff[b + 1];
    if (tid < BK_NODES) cnt[tid] = 0;
    __syncthreads();
    for (int j = beg + tid; j < end; j += 256)
        atomicAdd(&cnt[bbuf[j] & (BK_NODES - 1)], 1);
    __syncthreads();
    if (tid < BK_NODES) sc[tid] = cnt[tid];
    __syncthreads();
    for (int d = 1; d < BK_NODES; d <<= 1) {
        int v = (tid >= d && tid < BK_NODES) ? sc[tid - d] : 0;
        __syncthreads();
        if (tid < BK_NODES) sc[tid] += v;
        __syncthreads();
    }
    if (tid < BK_NODES) {
        int node = b * BK_NODES + tid;
        int start = beg + sc[tid] - cnt[tid];
        cur[tid] = start;
        if (node < N) {
            offsets[node] = start;
            dinv[node] = rsqrtf((float)(cnt[tid] + 1));   // +1 self loop
        }
    }
    __syncthreads();
    for (int j = beg + tid; j < end; j += 256) {
        int packed = bbuf[j];
        int pos = atomicAdd(&cur[packed & (BK_NODES - 1)], 1);
        csr_src[pos] = packed >> BK_SHIFT;
    }
}

// ---------------- W (f32, row-major [k][c]) -> Wt (bf16, [c][k]) ----------------
__global__ __launch_bounds__(256) void wconv_kernel(const float* __restrict__ W,
                                                    ushort* __restrict__ Wt) {
    int idx = blockIdx.x * 256 + threadIdx.x;
    if (idx < DIM * DIM) {
        int k = idx >> 7, c = idx & (DIM - 1);
        Wt[c * DIM + k] = (ushort)bf16_rne(W[idx]);
    }
}

// ---------------- pre-scale: y[i] = bf16(dinv[i] * x[i]) ----------------
__global__ __launch_bounds__(256) void prescale_kernel(const float* __restrict__ x,
                                                       const float* __restrict__ dinv,
                                                       ushort* __restrict__ y, int N) {
    int t = blockIdx.x * 256 + threadIdx.x;   // one float4 -> 4 bf16 (8B)
    int total = N * (DIM / 4);
    if (t < total) {
        int row = t >> 5;
        float di = dinv[row];
        float4 v = ((const float4*)x)[t];
        uint2 o;
        o.x = bf16_rne(v.x * di) | (bf16_rne(v.y * di) << 16);
        o.y = bf16_rne(v.z * di) | (bf16_rne(v.w * di) << 16);
        ((uint2*)y)[t] = o;
    }
}

// ---------------- aggregation: h[d] = bf16( dinv[d]*(y[d] + sum_e y[src]) ), f32 accumulate ----------------
__global__ __launch_bounds__(256) void agg_kernel(const ushort* __restrict__ y,
                                                  const int* __restrict__ csr_src,
                                                  const int* __restrict__ offsets,
                                                  const float* __restrict__ dinv,
                                                  ushort* __restrict__ h, int N) {
    int lane = threadIdx.x & 63;
    int wid  = __builtin_amdgcn_readfirstlane((int)(threadIdx.x >> 6));
    int node = blockIdx.x * 4 + wid;
    if (node >= N) return;
    int beg = offsets[node];
    int end = offsets[node + 1];
    float di = dinv[node];
    unsigned v = ((const unsigned*)(y + (size_t)node * DIM))[lane];   // self term (already dinv-scaled)
    float ax = __uint_as_float(v << 16);
    float ay = __uint_as_float(v & 0xffff0000u);
    int j = beg;
    for (; j + 4 <= end; j += 4) {
        int s0 = csr_src[j + 0], s1 = csr_src[j + 1];
        int s2 = csr_src[j + 2], s3 = csr_src[j + 3];
        unsigned v0 = ((const unsigned*)(y + (size_t)s0 * DIM))[lane];
        unsigned v1 = ((const unsigned*)(y + (size_t)s1 * DIM))[lane];
        unsigned v2 = ((const unsigned*)(y + (size_t)s2 * DIM))[lane];
        unsigned v3 = ((const unsigned*)(y + (size_t)s3 * DIM))[lane];
        ax += __uint_as_float(v0 << 16); ay += __uint_as_float(v0 & 0xffff0000u);
        ax += __uint_as_float(v1 << 16); ay += __uint_as_float(v1 & 0xffff0000u);
        ax += __uint_as_float(v2 << 16); ay += __uint_as_float(v2 & 0xffff0000u);
        ax += __uint_as_float(v3 << 16); ay += __uint_as_float(v3 & 0xffff0000u);
    }
    for (; j < end; ++j) {
        int s = csr_src[j];
        unsigned vv = ((const unsigned*)(y + (size_t)s * DIM))[lane];
        ax += __uint_as_float(vv << 16); ay += __uint_as_float(vv & 0xffff0000u);
    }
    ax *= di; ay *= di;
    ((unsigned*)(h + (size_t)node * DIM))[lane] = bf16_rne(ax) | (bf16_rne(ay) << 16);
}

// ---------------- MFMA GEMM + bias + PReLU: out = prelu(h @ W + b) ----------------
// wave = 16 rows; 8 col-tiles of 16; K=128 in 4 steps of 32.
// A frag: h[m=lane&15][k=quad*8+j]; B frag: Wt[col=lane&15][k=quad*8+j] (contiguous);
// D: col=lane&15, row=quad*4+reg  (verified layouts, learn_hip m89/m120).
__global__ __launch_bounds__(256) void gemm_kernel(const ushort* __restrict__ h,
                                                   const ushort* __restrict__ Wt,
                                                   const float* __restrict__ bias,
                                                   const float* __restrict__ alpha,
                                                   float* __restrict__ out, int N) {
    int lane = threadIdx.x & 63;
    int wv   = threadIdx.x >> 6;
    int rowbase = (blockIdx.x * 4 + wv) * 16;
    int r = lane & 15, quad = lane >> 4;
    f32x4 acc[8];
    #pragma unroll
    for (int ct = 0; ct < 8; ++ct) acc[ct] = (f32x4){0.f, 0.f, 0.f, 0.f};
    int arow = rowbase + r;
    if (arow >= N) arow = N - 1;                       // safe clamp for tail loads
    const ushort* ap = h + (size_t)arow * DIM + quad * 8;
    #pragma unroll
    for (int ks = 0; ks < 4; ++ks) {
        bf16x8 a = *(const bf16x8*)(ap + ks * 32);
        #pragma unroll
        for (int ct = 0; ct < 8; ++ct) {
            bf16x8 b = *(const bf16x8*)(Wt + (size_t)(ct * 16 + r) * DIM + ks * 32 + quad * 8);
            acc[ct] = __builtin_amdgcn_mfma_f32_16x16x32_bf16(a, b, acc[ct], 0, 0, 0);
        }
    }
    #pragma unroll
    for (int ct = 0; ct < 8; ++ct) {
        int col = ct * 16 + r;
        float bb = bias[col], al = alpha[col];
        #pragma unroll
        for (int reg = 0; reg < 4; ++reg) {
            int grow = rowbase + quad * 4 + reg;
            if (grow < N) {
                float vv = acc[ct][reg] + bb;
                vv = vv > 0.f ? vv : al * vv;
                out[(size_t)grow * DIM + col] = vv;
            }
        }
    }
}

extern "C" void kernel_launch(void* const* d_in, const int* in_sizes, int n_in,
                              void* d_out, int out_size, void* d_ws, size_t ws_size,
                              hipStream_t stream) {
    const float* x     = (const float*)d_in[0];
    const int*   ei    = (const int*)d_in[1];
    const float* W     = (const float*)d_in[2];
    const float* b     = (const float*)d_in[3];
    const float* alpha = (const float*)d_in[4];
    float* out = (float*)d_out;

    int N = in_sizes[0] / DIM;
    int E = in_sizes[1] / 2;
    const int* src = ei;
    const int* dst = ei + E;
    int nbk = (N + BK_NODES - 1) >> BK_SHIFT;      // 782 for N=100000

    char* ws = (char*)d_ws;
    size_t off = 0;
    auto alloc = [&](size_t bytes) -> char* {
        char* p = ws + off;
        off += (bytes + 255) & ~(size_t)255;
        return p;
    };
    int*    bcount  = (int*)alloc((size_t)MAX_BUCKETS * 4);
    int*    boff    = (int*)alloc((size_t)(MAX_BUCKETS + 1) * 4);
    int*    bcursor = (int*)alloc((size_t)MAX_BUCKETS * CUR_STRIDE * 4);
    int*    offsets = (int*)alloc((size_t)(N + 1) * 4);
    float*  dinv    = (float*)alloc((size_t)N * 4);
    int*    bbuf    = (int*)alloc((size_t)E * 4);
    int*    csr_src = (int*)alloc((size_t)E * 4);
    ushort* y       = (ushort*)alloc((size_t)N * DIM * 2);   // bf16
    ushort* h       = (ushort*)alloc((size_t)N * DIM * 2);   // bf16
    ushort* Wt      = (ushort*)alloc((size_t)DIM * DIM * 2); // bf16 transposed
    // total ~64.9 MB; R4 proved >=65.4 MB available (agg_kernel branch ran)

    hipMemsetAsync(bcount, 0, (size_t)nbk * 4, stream);
    bucket_hist_kernel<<<(E + 2047) / 2048, 256, 0, stream>>>(dst, bcount, E, nbk);
    bucket_scan_kernel<<<1, MAX_BUCKETS, 0, stream>>>(bcount, boff, bcursor, offsets, nbk, N, E);
    bucket_scatter_kernel<<<(E + ST - 1) / ST, 256, 0, stream>>>(src, dst, bcursor, bbuf, E, nbk);
    build_csr_kernel<<<nbk, 256, 0, stream>>>(bbuf, boff, offsets, dinv, csr_src, N);
    wconv_kernel<<<(DIM * DIM + 255) / 256, 256, 0, stream>>>(W, Wt);
    prescale_kernel<<<(N * (DIM / 4) + 255) / 256, 256, 0, stream>>>(x, dinv, y, N);
    agg_kernel<<<(N + 3) / 4, 256, 0, stream>>>(y, csr_src, offsets, dinv, h, N);
    gemm_kernel<<<(N + 63) / 64, 256, 0, stream>>>(h, Wt, b, alpha, out, N);
}